// Round 2
// baseline (344.198 us; speedup 1.0000x reference)
//
#include <hip/hip_runtime.h>

#define NSLOPE 0.2f
#define CAP 128            // bucket capacity per dst node (max degree ~66 incl. self-loop)

typedef __bf16 bf16x8 __attribute__((ext_vector_type(8)));
typedef __bf16 bf16x4 __attribute__((ext_vector_type(4)));
typedef __bf16 bf16x2 __attribute__((ext_vector_type(2)));
typedef float  f32x4  __attribute__((ext_vector_type(4)));

typedef uint32_t __attribute__((address_space(1))) gbl_u32;
typedef uint32_t __attribute__((address_space(3))) lds_u32;

// ===== bucket fill: append edges after prep pre-inserted self-loops =========
__global__ void fill_kernel(const int* __restrict__ ei, int E,
                            int* cnt, int* __restrict__ col){
  int i = blockIdx.x*blockDim.x + threadIdx.x;
  if (i < E){
    int s = ei[i], d = ei[E + i];
    int slot = atomicAdd(&cnt[d], 1);
    if (slot < CAP) col[(d << 7) + slot] = s;   // CAP==128
  }
}

// ===== W [K][Nc] fp32 -> Bt [Nc][2K] bf16 split body (hi @ k, lo @ K+k) ====
__device__ __forceinline__ void wsplit_body(
    const float* __restrict__ W, __bf16* __restrict__ Bt, int K, int Nc,
    int kb, int nb, float (*hi_s)[33], float (*lo_s)[33]){
  int tx = threadIdx.x & 31, ty = threadIdx.x >> 5;   // 32 x 8
  int k0 = kb * 32, n0 = nb * 32;
#pragma unroll
  for (int i = 0; i < 4; i++){
    int r = ty + i*8;
    float v = W[(size_t)(k0 + r)*Nc + n0 + tx];
    float h = (float)(__bf16)v;
    hi_s[r][tx] = h;
    lo_s[r][tx] = v - h;
  }
  __syncthreads();
  int K2 = 2*K;
#pragma unroll
  for (int i = 0; i < 4; i++){
    int n = ty + i*8;
    Bt[(size_t)(n0 + n)*K2 + k0 + tx]     = (__bf16)hi_s[tx][n];
    Bt[(size_t)(n0 + n)*K2 + K + k0 + tx] = (__bf16)lo_s[tx][n];
  }
}

// ===== fused prep: cnt=1 + self-loop col + al zero + split(x) + wsplit(W*) ==
__global__ __launch_bounds__(256) void prep_kernel(
    const float* __restrict__ x, __bf16* __restrict__ X2,
    const float* __restrict__ W1, __bf16* __restrict__ B1t,
    const float* __restrict__ W2, __bf16* __restrict__ B2t,
    const float* __restrict__ W3, __bf16* __restrict__ B3t,
    int* __restrict__ cnt, int* __restrict__ col,
    float* __restrict__ albase, int N){
  __shared__ float hi_s[32][33], lo_s[32][33];
  int b = blockIdx.x, t = threadIdx.x;
  int gid = b*256 + t;
  if (gid < N){
    cnt[gid] = 1;                  // self-loop pre-count
    col[gid << 7] = gid;           // self-loop entry at slot 0
  }
  // zero al_s/al_d for all 3 layers: 18N floats contiguous, float4 stores
  if (gid*4 < N*18) *(float4*)(albase + gid*4) = make_float4(0.f,0.f,0.f,0.f);

  const int nb_split = (N*32 + 255) / 256;   // 1250
  if (b < nb_split){
    int i = gid * 4;
    if (i < N*128){
      int n = i >> 7, c = i & 127;
      float4 v = *(const float4*)(x + i);
      float f[4] = {v.x, v.y, v.z, v.w};
      bf16x4 h, l;
#pragma unroll
      for (int u = 0; u < 4; u++){
        __bf16 hh = (__bf16)f[u];
        h[u] = hh;
        l[u] = (__bf16)(f[u] - (float)hh);
      }
      *(bf16x4*)(X2 + (size_t)n*256 + c)       = h;
      *(bf16x4*)(X2 + (size_t)n*256 + 128 + c) = l;
    }
  } else if (b < nb_split + 64){
    int bb = b - nb_split;                   // W1: K=128 -> 4 x 16
    wsplit_body(W1, B1t, 128, 512, bb & 3, bb >> 2, hi_s, lo_s);
  } else if (b < nb_split + 64 + 256){
    int bb = b - nb_split - 64;              // W2: 16 x 16
    wsplit_body(W2, B2t, 512, 512, bb & 15, bb >> 4, hi_s, lo_s);
  } else {
    int bb = b - nb_split - 320;             // W3: 16 x 16
    wsplit_body(W3, B3t, 512, 512, bb & 15, bb >> 4, hi_s, lo_s);
  }
}

// ========== bf16 MFMA GEMM over K2=2K (hi|lo fold), bf16 output =============
// 128x128 tile, 256 thr, XCD-pinned row-panels, fused attention-dot epilogue.
// NEW: 2-phase double-buffered pipeline (T3 minimal): stage next K-tile into
// buf^1 BEFORE computing buf; raw s_barrier + explicit vmcnt(0) AFTER the
// MFMA cluster so the 8 in-flight global_load_lds land under compute.
// Rationale: grid is ~1 block/CU (no neighbor waves) -> the m97 syncthreads
// drain exposed full memory latency every K-step (MfmaUtil 8%).
template<int H>
__global__ __launch_bounds__(256) void gemm_mfma(
    const __bf16* __restrict__ A2, const __bf16* __restrict__ B2t,
    __bf16* __restrict__ Hb, const float* __restrict__ asrc,
    const float* __restrict__ adst, float* __restrict__ al_s,
    float* __restrict__ al_d, int M, int K2){
  __shared__ uint4 As[2048];   // 2 bufs x 16 fb x 64 lanes, 32 KiB
  __shared__ uint4 Bs[2048];   // 32 KiB
  int t = threadIdx.x, w = t >> 6, lane = t & 63;
  int mm = lane & 15, q = lane >> 4;

  int bid = blockIdx.x;
  int rowblk = (bid & 7) + ((bid >> 5) << 3);   // xcd + 8*rowgroup
  int cb = (bid >> 3) & 3;
  if (rowblk * 128 >= M) return;
  int bm = rowblk * 128;
  int bn = cb * 128;

  const __bf16* gA[4];
  const __bf16* gB[4];
#pragma unroll
  for (int jj = 0; jj < 4; jj++){
    int fb = w*4 + jj;
    int i = fb >> 1, s = fb & 1;
    int rowA = bm + i*16 + mm; rowA = (rowA < M) ? rowA : (M - 1);
    gA[jj] = A2 + (size_t)rowA*K2 + s*32 + q*8;
    int rowB = bn + i*16 + mm;
    gB[jj] = B2t + (size_t)rowB*K2 + s*32 + q*8;
  }

  f32x4 acc[4][4];
#pragma unroll
  for (int i = 0; i < 4; i++)
#pragma unroll
    for (int j = 0; j < 4; j++)
#pragma unroll
      for (int r = 0; r < 4; r++) acc[i][j][r] = 0.f;

#define STAGE(buf)                                                          \
  _Pragma("unroll")                                                         \
  for (int jj = 0; jj < 4; jj++){                                           \
    int fb = w*4 + jj;                                                      \
    __builtin_amdgcn_global_load_lds(                                       \
        (const gbl_u32*)gA[jj], (lds_u32*)(As + (buf)*1024 + fb*64), 16, 0, 0); \
    __builtin_amdgcn_global_load_lds(                                       \
        (const gbl_u32*)gB[jj], (lds_u32*)(Bs + (buf)*1024 + fb*64), 16, 0, 0); \
    gA[jj] += 64;                                                           \
    gB[jj] += 64;                                                           \
  }

#define COMPUTE(buf)                                                        \
  _Pragma("unroll")                                                         \
  for (int s = 0; s < 2; s++){                                              \
    bf16x8 af[4], bfr[4];                                                   \
    _Pragma("unroll")                                                       \
    for (int i2 = 0; i2 < 4; i2++){                                         \
      int fbA = ((((w & 1)*4) + i2) << 1) | s;                              \
      af[i2]  = *(bf16x8*)&As[(buf)*1024 + fbA*64 + lane];                  \
      int fbB = ((((w >> 1)*4) + i2) << 1) | s;                             \
      bfr[i2] = *(bf16x8*)&Bs[(buf)*1024 + fbB*64 + lane];                  \
    }                                                                       \
    _Pragma("unroll")                                                       \
    for (int i2 = 0; i2 < 4; i2++)                                          \
      _Pragma("unroll")                                                     \
      for (int j2 = 0; j2 < 4; j2++)                                        \
        acc[i2][j2] = __builtin_amdgcn_mfma_f32_16x16x32_bf16(              \
            af[i2], bfr[j2], acc[i2][j2], 0, 0, 0);                         \
  }

  const int niter = K2 >> 6;
  // prologue: stage tile 0, wait, barrier
  STAGE(0);
  asm volatile("s_waitcnt vmcnt(0)" ::: "memory");
  __builtin_amdgcn_s_barrier();
  int cur = 0;
  for (int it = 0; it < niter - 1; it++){
    STAGE(cur ^ 1);                 // issue next tile's loads (in flight)
    COMPUTE(cur);                   // ds_read + 32 MFMA hide the load latency
    asm volatile("s_waitcnt vmcnt(0)" ::: "memory");
    __builtin_amdgcn_s_barrier();
    cur ^= 1;
  }
  COMPUTE(cur);                     // last tile, no prefetch

#undef STAGE
#undef COMPUTE

  // ---- epilogue: Hb store + fused attention dots (f32 acc, atomic accum) ---
  // a_src/a_dst are head-concatenated [512] == Hb column space: index = colc.
  float as_v[4], ad_v[4];
#pragma unroll
  for (int j2 = 0; j2 < 4; j2++){
    int colc = bn + ((w >> 1)*4 + j2)*16 + mm;
    as_v[j2] = asrc[colc];
    ad_v[j2] = adst[colc];
  }
  const int h = (H == 4) ? (bn >> 7) : 0;
#pragma unroll
  for (int i2 = 0; i2 < 4; i2++){
    int rbase = bm + ((w & 1)*4 + i2)*16 + q*4;
#pragma unroll
    for (int j2 = 0; j2 < 4; j2++){
      int colc = bn + ((w >> 1)*4 + j2)*16 + mm;
#pragma unroll
      for (int r = 0; r < 4; r++){
        int row = rbase + r;
        if (row < M) Hb[(size_t)row*512 + colc] = (__bf16)acc[i2][j2][r];
      }
    }
#pragma unroll
    for (int r = 0; r < 4; r++){
      float ps = acc[i2][0][r]*as_v[0] + acc[i2][1][r]*as_v[1]
               + acc[i2][2][r]*as_v[2] + acc[i2][3][r]*as_v[3];
      float pd = acc[i2][0][r]*ad_v[0] + acc[i2][1][r]*ad_v[1]
               + acc[i2][2][r]*ad_v[2] + acc[i2][3][r]*ad_v[3];
#pragma unroll
      for (int off = 1; off < 16; off <<= 1){   // reduce over mm (16 cols)
        ps += __shfl_xor(ps, off);
        pd += __shfl_xor(pd, off);
      }
      int row = rbase + r;
      if (mm == 0 && row < M){
        atomicAdd(&al_s[(size_t)row*H + h], ps);
        atomicAdd(&al_d[(size_t)row*H + h], pd);
      }
    }
  }
}

// ====== channel-sliced gather with FUSED per-head softmax, XCD-pinned =======
template<int H, int MODE>
__global__ __launch_bounds__(64) void aggregate_slice(
    const __bf16* __restrict__ Hb, const float* __restrict__ al_s,
    const float* __restrict__ al_d, const int* __restrict__ cnt,
    const int* __restrict__ col, const float* __restrict__ bias,
    float* __restrict__ outF, __bf16* __restrict__ fhi,
    __bf16* __restrict__ flo, int fstride, int nidx, int N){
  int g = blockIdx.x;
  int x = g & 7, idx = g >> 3;
  int s = x >> 1, half = x & 1;
  int d = half * nidx + idx;
  if (d >= N) return;
  int lane = threadIdx.x;
  int start = d << 7;                    // CAP==128 bucket base
  int end = start + cnt[d];
  const int hh = (H == 1) ? 0 : s;
  const float ald = al_d[(size_t)d*H + hh];
  const bf16x2* __restrict__ Hb2 = (const bf16x2*)Hb;   // row = 256 units
  const size_t coff = s*64 + lane;

  float mx = -1e30f;
  for (int e = start + lane; e < end; e += 64){
    int sc = col[e];
    float v = al_s[(size_t)sc*H + hh] + ald;
    v = (v > 0.f) ? v : NSLOPE * v;
    mx = fmaxf(mx, v);
  }
#pragma unroll
  for (int off = 32; off > 0; off >>= 1)
    mx = fmaxf(mx, __shfl_xor(mx, off));

  __shared__ int   src_s[64];
  __shared__ float a_s[64];

  float ax0=0.f, ay0=0.f, ax1=0.f, ay1=0.f;
  float ax2=0.f, ay2=0.f, ax3=0.f, ay3=0.f;
  float lsum = 0.f;

  for (int c0 = start; c0 < end; c0 += 64){
    int cnt2 = min(64, end - c0);
    if (lane < cnt2){
      int e = c0 + lane;
      int sc = col[e];
      float v = al_s[(size_t)sc*H + hh] + ald;
      v = (v > 0.f) ? v : NSLOPE * v;
      float ev = __expf(v - mx);
      src_s[lane] = sc;
      a_s[lane]   = ev;
      lsum += ev;
    }
    __syncthreads();
    int i = 0;
    for (; i + 4 <= cnt2; i += 4){
      int s0 = src_s[i],   s1 = src_s[i+1];
      int s2 = src_s[i+2], s3 = src_s[i+3];
      float e0 = a_s[i],   e1 = a_s[i+1];
      float e2 = a_s[i+2], e3 = a_s[i+3];
      bf16x2 v0 = Hb2[(size_t)s0*256 + coff];
      bf16x2 v1 = Hb2[(size_t)s1*256 + coff];
      bf16x2 v2 = Hb2[(size_t)s2*256 + coff];
      bf16x2 v3 = Hb2[(size_t)s3*256 + coff];
      ax0 += e0*(float)v0[0]; ay0 += e0*(float)v0[1];
      ax1 += e1*(float)v1[0]; ay1 += e1*(float)v1[1];
      ax2 += e2*(float)v2[0]; ay2 += e2*(float)v2[1];
      ax3 += e3*(float)v3[0]; ay3 += e3*(float)v3[1];
    }
    for (; i < cnt2; i++){
      int s0 = src_s[i];
      float e0 = a_s[i];
      bf16x2 v0 = Hb2[(size_t)s0*256 + coff];
      ax0 += e0*(float)v0[0]; ay0 += e0*(float)v0[1];
    }
    __syncthreads();
  }

#pragma unroll
  for (int off = 32; off > 0; off >>= 1)
    lsum += __shfl_xor(lsum, off);

  float accx = (ax0 + ax1) + (ax2 + ax3);
  float accy = (ay0 + ay1) + (ay2 + ay3);
  float invd = 1.f / lsum;
  int c = s*128 + lane*2;
  float2 bv = *(const float2*)(bias + c);
  float r0 = accx * invd + bv.x;
  float r1 = accy * invd + bv.y;
  if (MODE == 1){
    r0 = fmaxf(r0, 0.f); r1 = fmaxf(r1, 0.f);
    __bf16 h0 = (__bf16)r0, h1 = (__bf16)r1;
    bf16x2 hv; hv[0] = h0; hv[1] = h1;
    bf16x2 lv; lv[0] = (__bf16)(r0 - (float)h0); lv[1] = (__bf16)(r1 - (float)h1);
    *(bf16x2*)(fhi + (size_t)d*fstride + c) = hv;
    *(bf16x2*)(flo + (size_t)d*fstride + c) = lv;
  } else {
    *(float2*)(outF + (size_t)d*512 + c) = make_float2(r0, r1);
  }
}

// =========================== launch =========================================
extern "C" void kernel_launch(void* const* d_in, const int* in_sizes, int n_in,
                              void* d_out, int out_size, void* d_ws, size_t ws_size,
                              hipStream_t stream){
  const float* x   = (const float*)d_in[0];
  const int*   ei  = (const int*)  d_in[1];
  const float* W1  = (const float*)d_in[2];
  const float* as1 = (const float*)d_in[3];
  const float* ad1 = (const float*)d_in[4];
  const float* b1  = (const float*)d_in[5];
  const float* W2  = (const float*)d_in[6];
  const float* as2 = (const float*)d_in[7];
  const float* ad2 = (const float*)d_in[8];
  const float* b2  = (const float*)d_in[9];
  const float* W3  = (const float*)d_in[10];
  const float* as3 = (const float*)d_in[11];
  const float* ad3 = (const float*)d_in[12];
  const float* b3  = (const float*)d_in[13];
  float* out = (float*)d_out;

  const int N = in_sizes[0] / 128;   // 10000
  const int E = in_sizes[1] / 2;     // 320000
  const int nidx = (N + 1) / 2;

  // workspace carve-up
  __bf16* feat2  = (__bf16*)d_ws;                     // N*1024 bf16 (hi|lo)
  __bf16* X2     = feat2 + (size_t)N*1024;            // N*256 bf16 (layer-1 A)
  float*  albase = (float*)(X2 + (size_t)N*256);      // 18*N floats total:
  float*  als1   = albase;                            //  N*4
  float*  ald1   = als1 + (size_t)N*4;                //  N*4
  float*  als2   = ald1 + (size_t)N*4;                //  N*4
  float*  ald2   = als2 + (size_t)N*4;                //  N*4
  float*  als3   = ald2 + (size_t)N*4;                //  N
  float*  ald3   = als3 + (size_t)N;                  //  N
  int*    cnt    = (int*)(ald3 + (size_t)N);          // N
  int*    col    = cnt + N;                           // N*CAP
  uintptr_t p  = (uintptr_t)(col + (size_t)N*CAP);
  p = (p + 15) & ~(uintptr_t)15;
  __bf16* B1t = (__bf16*)p;                           // 512*256 bf16
  __bf16* B2t = B1t + 512*256;                        // 512*1024 bf16
  __bf16* B3t = B2t + 512*1024;                       // 512*1024 bf16
  __bf16* Hb  = B3t + 512*1024;                       // N*512 bf16 (gather)

  const int nb_split = (N*32 + 255)/256;              // 1250
  const int pgrid = nb_split + 64 + 256 + 256;        // 1826

  // prep: cnt=1 + self-loop col + al-zero, split x, split W1/W2/W3
  prep_kernel<<<pgrid, 256, 0, stream>>>(x, X2, W1, B1t, W2, B2t, W3, B3t,
                                         cnt, col, albase, N);
  fill_kernel<<<(E+255)/256, 256, 0, stream>>>(ei, E, cnt, col);

  const int nrb = (N + 127)/128;                      // 79
  const int ggrid = (((nrb + 7) >> 3) << 3) * 4;      // 80*4 = 320 (XCD map)
  const int agrid = nidx * 8;

  // ---- layer 1: x[N,128] @ W1[128,512]  (K2 = 256) ----
  gemm_mfma<4><<<ggrid, 256, 0, stream>>>(X2, B1t, Hb, as1, ad1, als1, ald1, N, 256);
  aggregate_slice<4,1><<<agrid, 64, 0, stream>>>(Hb, als1, ald1, cnt, col, b1,
      (float*)nullptr, feat2, feat2 + 512, 1024, nidx, N);

  // ---- layer 2: feat[N,512] @ W2[512,512]  (K2 = 1024) ----
  gemm_mfma<4><<<ggrid, 256, 0, stream>>>(feat2, B2t, Hb, as2, ad2, als2, ald2, N, 1024);
  aggregate_slice<4,1><<<agrid, 64, 0, stream>>>(Hb, als2, ald2, cnt, col, b2,
      (float*)nullptr, feat2, feat2 + 512, 1024, nidx, N);

  // ---- layer 3: feat[N,512] @ W3[512,512], heads=1  (K2 = 1024) ----
  gemm_mfma<1><<<ggrid, 256, 0, stream>>>(feat2, B3t, Hb, as3, ad3, als3, ald3, N, 1024);
  aggregate_slice<1,0><<<agrid, 64, 0, stream>>>(Hb, als3, ald3, cnt, col, b3,
      out, (__bf16*)nullptr, (__bf16*)nullptr, 0, nidx, N);
}

// Round 3
// 335.030 us; speedup vs baseline: 1.0274x; 1.0274x over previous
//
#include <hip/hip_runtime.h>

#define NSLOPE 0.2f
#define CAP 128            // bucket capacity per dst node (max degree ~66 incl. self-loop)

typedef __bf16 bf16x8 __attribute__((ext_vector_type(8)));
typedef __bf16 bf16x4 __attribute__((ext_vector_type(4)));
typedef __bf16 bf16x2 __attribute__((ext_vector_type(2)));
typedef float  f32x4  __attribute__((ext_vector_type(4)));

typedef uint32_t __attribute__((address_space(1))) gbl_u32;
typedef uint32_t __attribute__((address_space(3))) lds_u32;

// ===== bucket fill: append edges after prep pre-inserted self-loops =========
__global__ void fill_kernel(const int* __restrict__ ei, int E,
                            int* cnt, int* __restrict__ col){
  int i = blockIdx.x*blockDim.x + threadIdx.x;
  if (i < E){
    int s = ei[i], d = ei[E + i];
    int slot = atomicAdd(&cnt[d], 1);
    if (slot < CAP) col[(d << 7) + slot] = s;   // CAP==128
  }
}

// ===== W [K][Nc] fp32 -> Bt [Nc][2K] bf16 split body (hi @ k, lo @ K+k) ====
__device__ __forceinline__ void wsplit_body(
    const float* __restrict__ W, __bf16* __restrict__ Bt, int K, int Nc,
    int kb, int nb, float (*hi_s)[33], float (*lo_s)[33]){
  int tx = threadIdx.x & 31, ty = threadIdx.x >> 5;   // 32 x 8
  int k0 = kb * 32, n0 = nb * 32;
#pragma unroll
  for (int i = 0; i < 4; i++){
    int r = ty + i*8;
    float v = W[(size_t)(k0 + r)*Nc + n0 + tx];
    float h = (float)(__bf16)v;
    hi_s[r][tx] = h;
    lo_s[r][tx] = v - h;
  }
  __syncthreads();
  int K2 = 2*K;
#pragma unroll
  for (int i = 0; i < 4; i++){
    int n = ty + i*8;
    Bt[(size_t)(n0 + n)*K2 + k0 + tx]     = (__bf16)hi_s[tx][n];
    Bt[(size_t)(n0 + n)*K2 + K + k0 + tx] = (__bf16)lo_s[tx][n];
  }
}

// ===== fused prep: cnt=1 + self-loop col + al zero + split(x) + wsplit(W*) ==
__global__ __launch_bounds__(256) void prep_kernel(
    const float* __restrict__ x, __bf16* __restrict__ X2,
    const float* __restrict__ W1, __bf16* __restrict__ B1t,
    const float* __restrict__ W2, __bf16* __restrict__ B2t,
    const float* __restrict__ W3, __bf16* __restrict__ B3t,
    int* __restrict__ cnt, int* __restrict__ col,
    float* __restrict__ albase, int N){
  __shared__ float hi_s[32][33], lo_s[32][33];
  int b = blockIdx.x, t = threadIdx.x;
  int gid = b*256 + t;
  if (gid < N){
    cnt[gid] = 1;                  // self-loop pre-count
    col[gid << 7] = gid;           // self-loop entry at slot 0
  }
  // zero al_s/al_d for all 3 layers: 18N floats contiguous, float4 stores
  if (gid*4 < N*18) *(float4*)(albase + gid*4) = make_float4(0.f,0.f,0.f,0.f);

  const int nb_split = (N*32 + 255) / 256;   // 1250
  if (b < nb_split){
    int i = gid * 4;
    if (i < N*128){
      int n = i >> 7, c = i & 127;
      float4 v = *(const float4*)(x + i);
      float f[4] = {v.x, v.y, v.z, v.w};
      bf16x4 h, l;
#pragma unroll
      for (int u = 0; u < 4; u++){
        __bf16 hh = (__bf16)f[u];
        h[u] = hh;
        l[u] = (__bf16)(f[u] - (float)hh);
      }
      *(bf16x4*)(X2 + (size_t)n*256 + c)       = h;
      *(bf16x4*)(X2 + (size_t)n*256 + 128 + c) = l;
    }
  } else if (b < nb_split + 64){
    int bb = b - nb_split;                   // W1: K=128 -> 4 x 16
    wsplit_body(W1, B1t, 128, 512, bb & 3, bb >> 2, hi_s, lo_s);
  } else if (b < nb_split + 64 + 256){
    int bb = b - nb_split - 64;              // W2: 16 x 16
    wsplit_body(W2, B2t, 512, 512, bb & 15, bb >> 4, hi_s, lo_s);
  } else {
    int bb = b - nb_split - 320;             // W3: 16 x 16
    wsplit_body(W3, B3t, 512, 512, bb & 15, bb >> 4, hi_s, lo_s);
  }
}

// ========== bf16 MFMA GEMM over K2=2K (hi|lo fold), bf16 output =============
// R2: BM=64, BN=128 tile -> 640 blocks (~2.5 blocks/CU co-resident) so the
// m97 single-buffer 2-barrier loop gets its cross-block latency hiding back
// (m114 mechanism). The R1 explicit dbuf is reverted: hipcc orders ds_read
// after in-flight global_load_lds (LDS alias) so it bought nothing (51 us).
// 4 waves: wave w -> rows (w&1)*32..+32, cols (w>>1)*64..+64 of the tile.
// LDS 24 KiB: As 8 fb (4 row-blk x 2 kslice), Bs 16 fb; fb = 16 rows x 32 k
// as 64 lanes x 16B. Each wave stages 6 fbs/iter via global_load_lds w=16.
template<int H>
__global__ __launch_bounds__(256) void gemm_mfma(
    const __bf16* __restrict__ A2, const __bf16* __restrict__ B2t,
    __bf16* __restrict__ Hb, const float* __restrict__ asrc,
    const float* __restrict__ adst, float* __restrict__ al_s,
    float* __restrict__ al_d, int M, int K2){
  __shared__ uint4 As[512];    // 8 fb x 64 lanes, 8 KiB
  __shared__ uint4 Bs[1024];   // 16 fb x 64 lanes, 16 KiB
  int t = threadIdx.x, w = t >> 6, lane = t & 63;
  int mm = lane & 15, q = lane >> 4;

  int bid = blockIdx.x;
  int idx = bid >> 3;
  int cb = idx & 3;
  int rowblk = (bid & 7) + ((idx >> 2) << 3);   // xcd-pinned row panels
  if (rowblk * 64 >= M) return;
  int bm = rowblk * 64, bn = cb * 128;
  int wr = w & 1, wc = w >> 1;

  // staging assignment: 24 fbs total, wave w stages fbs [w*6, w*6+6)
  const __bf16* gsrc[6];
  uint4* dstp[6];
#pragma unroll
  for (int jj = 0; jj < 6; jj++){
    int fg = w*6 + jj;
    if (fg < 8){                               // A fb: i = fg>>1, s = fg&1
      int i = fg >> 1, s = fg & 1;
      int rowA = bm + i*16 + mm; rowA = (rowA < M) ? rowA : (M - 1);
      gsrc[jj] = A2 + (size_t)rowA*K2 + s*32 + q*8;
      dstp[jj] = As + fg*64;
    } else {                                   // B fb
      int f = fg - 8, i = f >> 1, s = f & 1;
      int rowB = bn + i*16 + mm;
      gsrc[jj] = B2t + (size_t)rowB*K2 + s*32 + q*8;
      dstp[jj] = Bs + f*64;
    }
  }

  f32x4 acc[2][4];
#pragma unroll
  for (int i = 0; i < 2; i++)
#pragma unroll
    for (int j = 0; j < 4; j++)
#pragma unroll
      for (int r = 0; r < 4; r++) acc[i][j][r] = 0.f;

  const int niter = K2 >> 6;
  for (int it = 0; it < niter; it++){
    __syncthreads();
#pragma unroll
    for (int jj = 0; jj < 6; jj++){
      __builtin_amdgcn_global_load_lds(
          (const gbl_u32*)gsrc[jj], (lds_u32*)dstp[jj], 16, 0, 0);
      gsrc[jj] += 64;
    }
    __syncthreads();
#pragma unroll
    for (int s = 0; s < 2; s++){
      bf16x8 af[2], bfr[4];
#pragma unroll
      for (int i2 = 0; i2 < 2; i2++)
        af[i2] = *(bf16x8*)&As[((((wr*2) + i2) << 1) | s)*64 + lane];
#pragma unroll
      for (int j2 = 0; j2 < 4; j2++)
        bfr[j2] = *(bf16x8*)&Bs[((((wc*4) + j2) << 1) | s)*64 + lane];
#pragma unroll
      for (int i2 = 0; i2 < 2; i2++)
#pragma unroll
        for (int j2 = 0; j2 < 4; j2++)
          acc[i2][j2] = __builtin_amdgcn_mfma_f32_16x16x32_bf16(
              af[i2], bfr[j2], acc[i2][j2], 0, 0, 0);
    }
  }

  // ---- epilogue: Hb store + fused attention dots (f32 acc, atomic accum) ---
  // a_src/a_dst are head-concatenated [512] == Hb column space: index = colc.
  float as_v[4], ad_v[4];
#pragma unroll
  for (int j2 = 0; j2 < 4; j2++){
    int colc = bn + (wc*4 + j2)*16 + mm;
    as_v[j2] = asrc[colc];
    ad_v[j2] = adst[colc];
  }
  const int h = (H == 4) ? (bn >> 7) : 0;
#pragma unroll
  for (int i2 = 0; i2 < 2; i2++){
    int rbase = bm + (wr*2 + i2)*16 + q*4;
#pragma unroll
    for (int j2 = 0; j2 < 4; j2++){
      int colc = bn + (wc*4 + j2)*16 + mm;
#pragma unroll
      for (int r = 0; r < 4; r++){
        int row = rbase + r;
        if (row < M) Hb[(size_t)row*512 + colc] = (__bf16)acc[i2][j2][r];
      }
    }
#pragma unroll
    for (int r = 0; r < 4; r++){
      float ps = acc[i2][0][r]*as_v[0] + acc[i2][1][r]*as_v[1]
               + acc[i2][2][r]*as_v[2] + acc[i2][3][r]*as_v[3];
      float pd = acc[i2][0][r]*ad_v[0] + acc[i2][1][r]*ad_v[1]
               + acc[i2][2][r]*ad_v[2] + acc[i2][3][r]*ad_v[3];
#pragma unroll
      for (int off = 1; off < 16; off <<= 1){   // reduce over mm (16 cols)
        ps += __shfl_xor(ps, off);
        pd += __shfl_xor(pd, off);
      }
      int row = rbase + r;
      if (mm == 0 && row < M){
        atomicAdd(&al_s[(size_t)row*H + h], ps);
        atomicAdd(&al_d[(size_t)row*H + h], pd);
      }
    }
  }
}

// ====== channel-sliced gather with FUSED per-head softmax, XCD-pinned =======
template<int H, int MODE>
__global__ __launch_bounds__(64) void aggregate_slice(
    const __bf16* __restrict__ Hb, const float* __restrict__ al_s,
    const float* __restrict__ al_d, const int* __restrict__ cnt,
    const int* __restrict__ col, const float* __restrict__ bias,
    float* __restrict__ outF, __bf16* __restrict__ fhi,
    __bf16* __restrict__ flo, int fstride, int nidx, int N){
  int g = blockIdx.x;
  int x = g & 7, idx = g >> 3;
  int s = x >> 1, half = x & 1;
  int d = half * nidx + idx;
  if (d >= N) return;
  int lane = threadIdx.x;
  int start = d << 7;                    // CAP==128 bucket base
  int end = start + cnt[d];
  const int hh = (H == 1) ? 0 : s;
  const float ald = al_d[(size_t)d*H + hh];
  const bf16x2* __restrict__ Hb2 = (const bf16x2*)Hb;   // row = 256 units
  const size_t coff = s*64 + lane;

  float mx = -1e30f;
  for (int e = start + lane; e < end; e += 64){
    int sc = col[e];
    float v = al_s[(size_t)sc*H + hh] + ald;
    v = (v > 0.f) ? v : NSLOPE * v;
    mx = fmaxf(mx, v);
  }
#pragma unroll
  for (int off = 32; off > 0; off >>= 1)
    mx = fmaxf(mx, __shfl_xor(mx, off));

  __shared__ int   src_s[64];
  __shared__ float a_s[64];

  float ax0=0.f, ay0=0.f, ax1=0.f, ay1=0.f;
  float ax2=0.f, ay2=0.f, ax3=0.f, ay3=0.f;
  float lsum = 0.f;

  for (int c0 = start; c0 < end; c0 += 64){
    int cnt2 = min(64, end - c0);
    if (lane < cnt2){
      int e = c0 + lane;
      int sc = col[e];
      float v = al_s[(size_t)sc*H + hh] + ald;
      v = (v > 0.f) ? v : NSLOPE * v;
      float ev = __expf(v - mx);
      src_s[lane] = sc;
      a_s[lane]   = ev;
      lsum += ev;
    }
    __syncthreads();
    int i = 0;
    for (; i + 4 <= cnt2; i += 4){
      int s0 = src_s[i],   s1 = src_s[i+1];
      int s2 = src_s[i+2], s3 = src_s[i+3];
      float e0 = a_s[i],   e1 = a_s[i+1];
      float e2 = a_s[i+2], e3 = a_s[i+3];
      bf16x2 v0 = Hb2[(size_t)s0*256 + coff];
      bf16x2 v1 = Hb2[(size_t)s1*256 + coff];
      bf16x2 v2 = Hb2[(size_t)s2*256 + coff];
      bf16x2 v3 = Hb2[(size_t)s3*256 + coff];
      ax0 += e0*(float)v0[0]; ay0 += e0*(float)v0[1];
      ax1 += e1*(float)v1[0]; ay1 += e1*(float)v1[1];
      ax2 += e2*(float)v2[0]; ay2 += e2*(float)v2[1];
      ax3 += e3*(float)v3[0]; ay3 += e3*(float)v3[1];
    }
    for (; i < cnt2; i++){
      int s0 = src_s[i];
      float e0 = a_s[i];
      bf16x2 v0 = Hb2[(size_t)s0*256 + coff];
      ax0 += e0*(float)v0[0]; ay0 += e0*(float)v0[1];
    }
    __syncthreads();
  }

#pragma unroll
  for (int off = 32; off > 0; off >>= 1)
    lsum += __shfl_xor(lsum, off);

  float accx = (ax0 + ax1) + (ax2 + ax3);
  float accy = (ay0 + ay1) + (ay2 + ay3);
  float invd = 1.f / lsum;
  int c = s*128 + lane*2;
  float2 bv = *(const float2*)(bias + c);
  float r0 = accx * invd + bv.x;
  float r1 = accy * invd + bv.y;
  if (MODE == 1){
    r0 = fmaxf(r0, 0.f); r1 = fmaxf(r1, 0.f);
    __bf16 h0 = (__bf16)r0, h1 = (__bf16)r1;
    bf16x2 hv; hv[0] = h0; hv[1] = h1;
    bf16x2 lv; lv[0] = (__bf16)(r0 - (float)h0); lv[1] = (__bf16)(r1 - (float)h1);
    *(bf16x2*)(fhi + (size_t)d*fstride + c) = hv;
    *(bf16x2*)(flo + (size_t)d*fstride + c) = lv;
  } else {
    *(float2*)(outF + (size_t)d*512 + c) = make_float2(r0, r1);
  }
}

// =========================== launch =========================================
extern "C" void kernel_launch(void* const* d_in, const int* in_sizes, int n_in,
                              void* d_out, int out_size, void* d_ws, size_t ws_size,
                              hipStream_t stream){
  const float* x   = (const float*)d_in[0];
  const int*   ei  = (const int*)  d_in[1];
  const float* W1  = (const float*)d_in[2];
  const float* as1 = (const float*)d_in[3];
  const float* ad1 = (const float*)d_in[4];
  const float* b1  = (const float*)d_in[5];
  const float* W2  = (const float*)d_in[6];
  const float* as2 = (const float*)d_in[7];
  const float* ad2 = (const float*)d_in[8];
  const float* b2  = (const float*)d_in[9];
  const float* W3  = (const float*)d_in[10];
  const float* as3 = (const float*)d_in[11];
  const float* ad3 = (const float*)d_in[12];
  const float* b3  = (const float*)d_in[13];
  float* out = (float*)d_out;

  const int N = in_sizes[0] / 128;   // 10000
  const int E = in_sizes[1] / 2;     // 320000
  const int nidx = (N + 1) / 2;

  // workspace carve-up
  __bf16* feat2  = (__bf16*)d_ws;                     // N*1024 bf16 (hi|lo)
  __bf16* X2     = feat2 + (size_t)N*1024;            // N*256 bf16 (layer-1 A)
  float*  albase = (float*)(X2 + (size_t)N*256);      // 18*N floats total:
  float*  als1   = albase;                            //  N*4
  float*  ald1   = als1 + (size_t)N*4;                //  N*4
  float*  als2   = ald1 + (size_t)N*4;                //  N*4
  float*  ald2   = als2 + (size_t)N*4;                //  N*4
  float*  als3   = ald2 + (size_t)N*4;                //  N
  float*  ald3   = als3 + (size_t)N;                  //  N
  int*    cnt    = (int*)(ald3 + (size_t)N);          // N
  int*    col    = cnt + N;                           // N*CAP
  uintptr_t p  = (uintptr_t)(col + (size_t)N*CAP);
  p = (p + 15) & ~(uintptr_t)15;
  __bf16* B1t = (__bf16*)p;                           // 512*256 bf16
  __bf16* B2t = B1t + 512*256;                        // 512*1024 bf16
  __bf16* B3t = B2t + 512*1024;                       // 512*1024 bf16
  __bf16* Hb  = B3t + 512*1024;                       // N*512 bf16 (gather)

  const int nb_split = (N*32 + 255)/256;              // 1250
  const int pgrid = nb_split + 64 + 256 + 256;        // 1826

  // prep: cnt=1 + self-loop col + al-zero, split x, split W1/W2/W3
  prep_kernel<<<pgrid, 256, 0, stream>>>(x, X2, W1, B1t, W2, B2t, W3, B3t,
                                         cnt, col, albase, N);
  fill_kernel<<<(E+255)/256, 256, 0, stream>>>(ei, E, cnt, col);

  const int nrb = (N + 63)/64;                        // 157 row panels (BM=64)
  const int ggrid = (((nrb + 7) >> 3) << 3) * 4;      // 160*4 = 640 (XCD map)
  const int agrid = nidx * 8;

  // ---- layer 1: x[N,128] @ W1[128,512]  (K2 = 256) ----
  gemm_mfma<4><<<ggrid, 256, 0, stream>>>(X2, B1t, Hb, as1, ad1, als1, ald1, N, 256);
  aggregate_slice<4,1><<<agrid, 64, 0, stream>>>(Hb, als1, ald1, cnt, col, b1,
      (float*)nullptr, feat2, feat2 + 512, 1024, nidx, N);

  // ---- layer 2: feat[N,512] @ W2[512,512]  (K2 = 1024) ----
  gemm_mfma<4><<<ggrid, 256, 0, stream>>>(feat2, B2t, Hb, as2, ad2, als2, ald2, N, 1024);
  aggregate_slice<4,1><<<agrid, 64, 0, stream>>>(Hb, als2, ald2, cnt, col, b2,
      (float*)nullptr, feat2, feat2 + 512, 1024, nidx, N);

  // ---- layer 3: feat[N,512] @ W3[512,512], heads=1  (K2 = 1024) ----
  gemm_mfma<1><<<ggrid, 256, 0, stream>>>(feat2, B3t, Hb, as3, ad3, als3, ald3, N, 1024);
  aggregate_slice<1,0><<<agrid, 64, 0, stream>>>(Hb, als3, ald3, cnt, col, b3,
      out, (__bf16*)nullptr, (__bf16*)nullptr, 0, nidx, N);
}

// Round 5
// 304.875 us; speedup vs baseline: 1.1290x; 1.0989x over previous
//
#include <hip/hip_runtime.h>

#define NSLOPE 0.2f
#define CAP 128            // bucket capacity per dst node (max degree ~66 incl. self-loop)

typedef __bf16 bf16x8 __attribute__((ext_vector_type(8)));
typedef __bf16 bf16x4 __attribute__((ext_vector_type(4)));
typedef __bf16 bf16x2 __attribute__((ext_vector_type(2)));
typedef float  f32x4  __attribute__((ext_vector_type(4)));

// ============================================================================
// FRAME LAYOUT: matrix [R rows][K2 cols] bf16 stored as frames of 16 rows x
// 32 k. Frame (rb, kf) holds lane slot = (row&15) + 16*((k>>3)&3), elem k&7.
// Element addr (bf16 units) = rb*(K2*16) + kf*512 + slot*8 + (k&7).
// A GEMM fragment load is then ptr + f*512 + lane*8 : contiguous 1KB/instr.
// ============================================================================

// ===== bucket fill: append edges after prep pre-inserted self-loops =========
__global__ void fill_kernel(const int* __restrict__ ei, int E,
                            int* cnt, int* __restrict__ col){
  int i = blockIdx.x*blockDim.x + threadIdx.x;
  if (i < E){
    int s = ei[i], d = ei[E + i];
    int slot = atomicAdd(&cnt[d], 1);
    if (slot < CAP) col[(d << 7) + slot] = s;   // CAP==128
  }
}

// ===== W [K][Nc] fp32 -> frame-layout split B (hi @ k, lo @ K+k), K2=2K ====
__device__ __forceinline__ void wsplit_body(
    const float* __restrict__ W, __bf16* __restrict__ Bt, int K, int Nc,
    int kb, int nb, float (*hi_s)[33], float (*lo_s)[33]){
  int tx = threadIdx.x & 31, ty = threadIdx.x >> 5;   // 32 x 8
  int k0 = kb * 32, n0 = nb * 32;
#pragma unroll
  for (int i = 0; i < 4; i++){
    int r = ty + i*8;
    float v = W[(size_t)(k0 + r)*Nc + n0 + tx];
    float h = (float)(__bf16)v;
    hi_s[r][tx] = h;
    lo_s[r][tx] = v - h;
  }
  __syncthreads();
  const size_t K2x16 = (size_t)(2*K) * 16;     // 16-row block stride
  const size_t lo_off = (size_t)(K >> 5) * 512;
#pragma unroll
  for (int i = 0; i < 4; i++){
    int n = ty + i*8;
    int r = n0 + n;                            // B row = W col
    size_t a = (size_t)(r >> 4)*K2x16 + (size_t)(k0 >> 5)*512
             + (size_t)((r & 15) + 16*(tx >> 3))*8 + (tx & 7);
    Bt[a]          = (__bf16)hi_s[tx][n];
    Bt[a + lo_off] = (__bf16)lo_s[tx][n];
  }
}

// ===== fused prep: cnt=1 + self-loop col + al zero + split(x) + wsplit(W*) ==
__global__ __launch_bounds__(256) void prep_kernel(
    const float* __restrict__ x, __bf16* __restrict__ X2,
    const float* __restrict__ W1, __bf16* __restrict__ B1t,
    const float* __restrict__ W2, __bf16* __restrict__ B2t,
    const float* __restrict__ W3, __bf16* __restrict__ B3t,
    int* __restrict__ cnt, int* __restrict__ col,
    float* __restrict__ albase, int N){
  __shared__ float hi_s[32][33], lo_s[32][33];
  int b = blockIdx.x, t = threadIdx.x;
  int gid = b*256 + t;
  if (gid < N){
    cnt[gid] = 1;                  // self-loop pre-count
    col[gid << 7] = gid;           // self-loop entry at slot 0
  }
  // zero al_s/al_d for all 3 layers: 18N floats contiguous, float4 stores
  if (gid*4 < N*18) *(float4*)(albase + gid*4) = make_float4(0.f,0.f,0.f,0.f);

  const int nb_split = (N*32 + 255) / 256;   // 1250
  if (b < nb_split){
    int i = gid * 4;
    if (i < N*128){
      int n = i >> 7, c = i & 127;           // 4 consecutive channels, 8-aligned block
      float4 v = *(const float4*)(x + i);
      float f[4] = {v.x, v.y, v.z, v.w};
      bf16x4 h, l;
#pragma unroll
      for (int u = 0; u < 4; u++){
        __bf16 hh = (__bf16)f[u];
        h[u] = hh;
        l[u] = (__bf16)(f[u] - (float)hh);
      }
      // frame layout, K2=256: hi at k=c, lo at k=128+c (kf += 4)
      size_t a = (size_t)(n >> 4)*4096 + (size_t)(c >> 5)*512
               + (size_t)((n & 15) + 16*((c >> 3) & 3))*8 + (c & 7);
      *(bf16x4*)(X2 + a)        = h;
      *(bf16x4*)(X2 + a + 2048) = l;
    }
  } else if (b < nb_split + 64){
    int bb = b - nb_split;                   // W1: K=128 -> 4 x 16
    wsplit_body(W1, B1t, 128, 512, bb & 3, bb >> 2, hi_s, lo_s);
  } else if (b < nb_split + 64 + 256){
    int bb = b - nb_split - 64;              // W2: 16 x 16
    wsplit_body(W2, B2t, 512, 512, bb & 15, bb >> 4, hi_s, lo_s);
  } else {
    int bb = b - nb_split - 320;             // W3: 16 x 16
    wsplit_body(W3, B3t, 512, 512, bb & 15, bb >> 4, hi_s, lo_s);
  }
}

// ========== bf16 MFMA GEMM over K2=2K (hi|lo fold), bf16 output =============
// R3/R4: NO LDS, NO barriers. Operands in frame layout -> each fragment load
// is a contiguous 1KB coalesced global_load_dwordx4 straight to VGPRs. Waves
// slip independently; compiler pipelines loads across frames; TLP (~6 waves/
// CU) hides latency. Rationale: 3 prior LDS variants all pinned at 48-51us
// with all pipes <10% busy = barrier-coupled exposed latency + 16-segment
// scatter per staging instr. This removes both.
// BM=64 BN=128, 4 waves: wave w -> rows (w&1)*32..+32, cols (w>>1)*64..+64.
template<int H>
__global__ __launch_bounds__(256) void gemm_mfma(
    const __bf16* __restrict__ A2f, const __bf16* __restrict__ B2f,
    __bf16* __restrict__ Hb, const float* __restrict__ asrc,
    const float* __restrict__ adst, float* __restrict__ al_s,
    float* __restrict__ al_d, int M, int K2){
  int t = threadIdx.x, w = t >> 6, lane = t & 63;
  int mm = lane & 15, q = lane >> 4;

  int bid = blockIdx.x;
  int idx = bid >> 3;
  int cb = idx & 3;
  int rowblk = (bid & 7) + ((idx >> 2) << 3);   // xcd-pinned row panels
  if (rowblk * 64 >= M) return;
  int bm = rowblk * 64, bn = cb * 128;
  int wr = w & 1, wc = w >> 1;

  const int nf = K2 >> 5;                 // frames per row-block
  const int rbmax = (M >> 4) - 1;         // M is a multiple of 16
  const __bf16* pA0; const __bf16* pA1;
  const __bf16* pB0; const __bf16* pB1; const __bf16* pB2; const __bf16* pB3;
  {
    int rb0 = (bm >> 4) + wr*2;     rb0 = (rb0 <= rbmax) ? rb0 : rbmax;
    int rb1 = (bm >> 4) + wr*2 + 1; rb1 = (rb1 <= rbmax) ? rb1 : rbmax;
    pA0 = A2f + (size_t)rb0*nf*512 + lane*8;
    pA1 = A2f + (size_t)rb1*nf*512 + lane*8;
    int rbB = (bn >> 4) + wc*4;
    pB0 = B2f + (size_t)(rbB+0)*nf*512 + lane*8;
    pB1 = B2f + (size_t)(rbB+1)*nf*512 + lane*8;
    pB2 = B2f + (size_t)(rbB+2)*nf*512 + lane*8;
    pB3 = B2f + (size_t)(rbB+3)*nf*512 + lane*8;
  }

  f32x4 acc[2][4];
#pragma unroll
  for (int i = 0; i < 2; i++)
#pragma unroll
    for (int j = 0; j < 4; j++)
#pragma unroll
      for (int r = 0; r < 4; r++) acc[i][j][r] = 0.f;

#pragma unroll 4
  for (int f = 0; f < nf; f++){
    bf16x8 a0 = *(const bf16x8*)(pA0 + (size_t)f*512);
    bf16x8 a1 = *(const bf16x8*)(pA1 + (size_t)f*512);
    bf16x8 b0 = *(const bf16x8*)(pB0 + (size_t)f*512);
    bf16x8 b1 = *(const bf16x8*)(pB1 + (size_t)f*512);
    bf16x8 b2 = *(const bf16x8*)(pB2 + (size_t)f*512);
    bf16x8 b3 = *(const bf16x8*)(pB3 + (size_t)f*512);
    acc[0][0] = __builtin_amdgcn_mfma_f32_16x16x32_bf16(a0, b0, acc[0][0], 0, 0, 0);
    acc[0][1] = __builtin_amdgcn_mfma_f32_16x16x32_bf16(a0, b1, acc[0][1], 0, 0, 0);
    acc[0][2] = __builtin_amdgcn_mfma_f32_16x16x32_bf16(a0, b2, acc[0][2], 0, 0, 0);
    acc[0][3] = __builtin_amdgcn_mfma_f32_16x16x32_bf16(a0, b3, acc[0][3], 0, 0, 0);
    acc[1][0] = __builtin_amdgcn_mfma_f32_16x16x32_bf16(a1, b0, acc[1][0], 0, 0, 0);
    acc[1][1] = __builtin_amdgcn_mfma_f32_16x16x32_bf16(a1, b1, acc[1][1], 0, 0, 0);
    acc[1][2] = __builtin_amdgcn_mfma_f32_16x16x32_bf16(a1, b2, acc[1][2], 0, 0, 0);
    acc[1][3] = __builtin_amdgcn_mfma_f32_16x16x32_bf16(a1, b3, acc[1][3], 0, 0, 0);
  }

  // ---- epilogue: Hb store + fused attention dots (f32 acc, atomic accum) ---
  // a_src/a_dst are head-concatenated [512] == Hb column space: index = colc.
  float as_v[4], ad_v[4];
#pragma unroll
  for (int j2 = 0; j2 < 4; j2++){
    int colc = bn + (wc*4 + j2)*16 + mm;
    as_v[j2] = asrc[colc];
    ad_v[j2] = adst[colc];
  }
  const int h = (H == 4) ? (bn >> 7) : 0;
#pragma unroll
  for (int i2 = 0; i2 < 2; i2++){
    int rbase = bm + (wr*2 + i2)*16 + q*4;
#pragma unroll
    for (int j2 = 0; j2 < 4; j2++){
      int colc = bn + (wc*4 + j2)*16 + mm;
#pragma unroll
      for (int r = 0; r < 4; r++){
        int row = rbase + r;
        if (row < M) Hb[(size_t)row*512 + colc] = (__bf16)acc[i2][j2][r];
      }
    }
#pragma unroll
    for (int r = 0; r < 4; r++){
      float ps = acc[i2][0][r]*as_v[0] + acc[i2][1][r]*as_v[1]
               + acc[i2][2][r]*as_v[2] + acc[i2][3][r]*as_v[3];
      float pd = acc[i2][0][r]*ad_v[0] + acc[i2][1][r]*ad_v[1]
               + acc[i2][2][r]*ad_v[2] + acc[i2][3][r]*ad_v[3];
#pragma unroll
      for (int off = 1; off < 16; off <<= 1){   // reduce over mm (16 cols)
        ps += __shfl_xor(ps, off);
        pd += __shfl_xor(pd, off);
      }
      int row = rbase + r;
      if (mm == 0 && row < M){
        atomicAdd(&al_s[(size_t)row*H + h], ps);
        atomicAdd(&al_d[(size_t)row*H + h], pd);
      }
    }
  }
}

// ====== channel-sliced gather with FUSED per-head softmax, XCD-pinned =======
// MODE==1 writes the next layer's A in FRAME layout (hi at k=c, lo at k=512+c,
// K2=1024: rb stride 16384, lo offset = 16 frames = 8192).
template<int H, int MODE>
__global__ __launch_bounds__(64) void aggregate_slice(
    const __bf16* __restrict__ Hb, const float* __restrict__ al_s,
    const float* __restrict__ al_d, const int* __restrict__ cnt,
    const int* __restrict__ col, const float* __restrict__ bias,
    float* __restrict__ outF, __bf16* __restrict__ fA,
    int nidx, int N){
  int g = blockIdx.x;
  int x = g & 7, idx = g >> 3;
  int s = x >> 1, half = x & 1;
  int d = half * nidx + idx;
  if (d >= N) return;
  int lane = threadIdx.x;
  int start = d << 7;                    // CAP==128 bucket base
  int end = start + cnt[d];
  const int hh = (H == 1) ? 0 : s;
  const float ald = al_d[(size_t)d*H + hh];
  const bf16x2* __restrict__ Hb2 = (const bf16x2*)Hb;   // row = 256 units
  const size_t coff = s*64 + lane;

  float mx = -1e30f;
  for (int e = start + lane; e < end; e += 64){
    int sc = col[e];
    float v = al_s[(size_t)sc*H + hh] + ald;
    v = (v > 0.f) ? v : NSLOPE * v;
    mx = fmaxf(mx, v);
  }
#pragma unroll
  for (int off = 32; off > 0; off >>= 1)
    mx = fmaxf(mx, __shfl_xor(mx, off));

  __shared__ int   src_s[64];
  __shared__ float a_s[64];

  float ax0=0.f, ay0=0.f, ax1=0.f, ay1=0.f;
  float ax2=0.f, ay2=0.f, ax3=0.f, ay3=0.f;
  float lsum = 0.f;

  for (int c0 = start; c0 < end; c0 += 64){
    int cnt2 = min(64, end - c0);
    if (lane < cnt2){
      int e = c0 + lane;
      int sc = col[e];
      float v = al_s[(size_t)sc*H + hh] + ald;
      v = (v > 0.f) ? v : NSLOPE * v;
      float ev = __expf(v - mx);
      src_s[lane] = sc;
      a_s[lane]   = ev;
      lsum += ev;
    }
    __syncthreads();
    int i = 0;
    for (; i + 4 <= cnt2; i += 4){
      int s0 = src_s[i],   s1 = src_s[i+1];
      int s2 = src_s[i+2], s3 = src_s[i+3];
      float e0 = a_s[i],   e1 = a_s[i+1];
      float e2 = a_s[i+2], e3 = a_s[i+3];
      bf16x2 v0 = Hb2[(size_t)s0*256 + coff];
      bf16x2 v1 = Hb2[(size_t)s1*256 + coff];
      bf16x2 v2 = Hb2[(size_t)s2*256 + coff];
      bf16x2 v3 = Hb2[(size_t)s3*256 + coff];
      ax0 += e0*(float)v0[0]; ay0 += e0*(float)v0[1];
      ax1 += e1*(float)v1[0]; ay1 += e1*(float)v1[1];
      ax2 += e2*(float)v2[0]; ay2 += e2*(float)v2[1];
      ax3 += e3*(float)v3[0]; ay3 += e3*(float)v3[1];
    }
    for (; i < cnt2; i++){
      int s0 = src_s[i];
      float e0 = a_s[i];
      bf16x2 v0 = Hb2[(size_t)s0*256 + coff];
      ax0 += e0*(float)v0[0]; ay0 += e0*(float)v0[1];
    }
    __syncthreads();
  }

#pragma unroll
  for (int off = 32; off > 0; off >>= 1)
    lsum += __shfl_xor(lsum, off);

  float accx = (ax0 + ax1) + (ax2 + ax3);
  float accy = (ay0 + ay1) + (ay2 + ay3);
  float invd = 1.f / lsum;
  int c = s*128 + lane*2;
  float2 bv = *(const float2*)(bias + c);
  float r0 = accx * invd + bv.x;
  float r1 = accy * invd + bv.y;
  if (MODE == 1){
    r0 = fmaxf(r0, 0.f); r1 = fmaxf(r1, 0.f);
    __bf16 h0 = (__bf16)r0, h1 = (__bf16)r1;
    bf16x2 hv; hv[0] = h0; hv[1] = h1;
    bf16x2 lv; lv[0] = (__bf16)(r0 - (float)h0); lv[1] = (__bf16)(r1 - (float)h1);
    // frame layout write (K2=1024): hi at k=c, lo at k=512+c
    size_t a = (size_t)(d >> 4)*16384 + (size_t)(c >> 5)*512
             + (size_t)((d & 15) + 16*((c >> 3) & 3))*8 + (c & 7);
    *(bf16x2*)(fA + a)        = hv;
    *(bf16x2*)(fA + a + 8192) = lv;
  } else {
    *(float2*)(outF + (size_t)d*512 + c) = make_float2(r0, r1);
  }
}

// =========================== launch =========================================
extern "C" void kernel_launch(void* const* d_in, const int* in_sizes, int n_in,
                              void* d_out, int out_size, void* d_ws, size_t ws_size,
                              hipStream_t stream){
  const float* x   = (const float*)d_in[0];
  const int*   ei  = (const int*)  d_in[1];
  const float* W1  = (const float*)d_in[2];
  const float* as1 = (const float*)d_in[3];
  const float* ad1 = (const float*)d_in[4];
  const float* b1  = (const float*)d_in[5];
  const float* W2  = (const float*)d_in[6];
  const float* as2 = (const float*)d_in[7];
  const float* ad2 = (const float*)d_in[8];
  const float* b2  = (const float*)d_in[9];
  const float* W3  = (const float*)d_in[10];
  const float* as3 = (const float*)d_in[11];
  const float* ad3 = (const float*)d_in[12];
  const float* b3  = (const float*)d_in[13];
  float* out = (float*)d_out;

  const int N = in_sizes[0] / 128;   // 10000
  const int E = in_sizes[1] / 2;     // 320000
  const int nidx = (N + 1) / 2;

  // workspace carve-up
  __bf16* feat2  = (__bf16*)d_ws;                     // N*1024 bf16 (frame, hi|lo)
  __bf16* X2     = feat2 + (size_t)N*1024;            // N*256 bf16 (frame, layer-1 A)
  float*  albase = (float*)(X2 + (size_t)N*256);      // 18*N floats total:
  float*  als1   = albase;                            //  N*4
  float*  ald1   = als1 + (size_t)N*4;                //  N*4
  float*  als2   = ald1 + (size_t)N*4;                //  N*4
  float*  ald2   = als2 + (size_t)N*4;                //  N*4
  float*  als3   = ald2 + (size_t)N*4;                //  N
  float*  ald3   = als3 + (size_t)N;                  //  N
  int*    cnt    = (int*)(ald3 + (size_t)N);          // N
  int*    col    = cnt + N;                           // N*CAP
  uintptr_t p  = (uintptr_t)(col + (size_t)N*CAP);
  p = (p + 15) & ~(uintptr_t)15;
  __bf16* B1t = (__bf16*)p;                           // 512*256 bf16 (frame)
  __bf16* B2t = B1t + 512*256;                        // 512*1024 bf16 (frame)
  __bf16* B3t = B2t + 512*1024;                       // 512*1024 bf16 (frame)
  __bf16* Hb  = B3t + 512*1024;                       // N*512 bf16 (row-major, gather)

  const int nb_split = (N*32 + 255)/256;              // 1250
  const int pgrid = nb_split + 64 + 256 + 256;        // 1826

  // prep: cnt=1 + self-loop col + al-zero, split x, split W1/W2/W3
  prep_kernel<<<pgrid, 256, 0, stream>>>(x, X2, W1, B1t, W2, B2t, W3, B3t,
                                         cnt, col, albase, N);
  fill_kernel<<<(E+255)/256, 256, 0, stream>>>(ei, E, cnt, col);

  const int nrb = (N + 63)/64;                        // 157 row panels (BM=64)
  const int ggrid = (((nrb + 7) >> 3) << 3) * 4;      // 160*4 = 640 (XCD map)
  const int agrid = nidx * 8;

  // ---- layer 1: x[N,128] @ W1[128,512]  (K2 = 256) ----
  gemm_mfma<4><<<ggrid, 256, 0, stream>>>(X2, B1t, Hb, as1, ad1, als1, ald1, N, 256);
  aggregate_slice<4,1><<<agrid, 64, 0, stream>>>(Hb, als1, ald1, cnt, col, b1,
      (float*)nullptr, feat2, nidx, N);

  // ---- layer 2: feat[N,512] @ W2[512,512]  (K2 = 1024) ----
  gemm_mfma<4><<<ggrid, 256, 0, stream>>>(feat2, B2t, Hb, as2, ad2, als2, ald2, N, 1024);
  aggregate_slice<4,1><<<agrid, 64, 0, stream>>>(Hb, als2, ald2, cnt, col, b2,
      (float*)nullptr, feat2, nidx, N);

  // ---- layer 3: feat[N,512] @ W3[512,512], heads=1  (K2 = 1024) ----
  gemm_mfma<1><<<ggrid, 256, 0, stream>>>(feat2, B3t, Hb, as3, ad3, als3, ald3, N, 1024);
  aggregate_slice<1,0><<<agrid, 64, 0, stream>>>(Hb, als3, ald3, cnt, col, b3,
      out, (__bf16*)nullptr, nidx, N);
}